// Round 1
// baseline (574.569 us; speedup 1.0000x reference)
//
#include <hip/hip_runtime.h>

#define GDIM   2045
#define BATCH  8
#define NLOCS  1024
#define TABLE  8192   // hash slots; 4096 candidates -> load factor 0.5

// ---------------- Kernel 1: dense base-map fill ----------------
// out[b][row][col][0..3] = {0.634, 0.634, xs[col], xs[row]}
// grid: x = ceil(G/256), y = BATCH*G ; one float4 store per thread.
__global__ __launch_bounds__(256) void fill_kernel(float* __restrict__ out) {
    const float DELTA_MAP = (511.0f - 0.5f) / 2045.0f;   // matches jnp fp32
    int col = blockIdx.x * 256 + threadIdx.x;
    if (col >= GDIM) return;
    int by  = blockIdx.y;            // = b*G + row
    int row = by % GDIM;             // uniform per block -> SALU magic-mul
    float4 v;
    v.x = 0.634f;
    v.y = 0.634f;
    v.z = 0.5f + DELTA_MAP * (float)col;   // gx: varies along cols (channel 2)
    v.w = 0.5f + DELTA_MAP * (float)row;   // gy: varies along rows (channel 3)
    reinterpret_cast<float4*>(out)[(size_t)by * GDIM + col] = v;
}

// ---------------- Kernel 2: sparse hit scatter ----------------
// One block per batch. Resolve per-cell winner = max ordinal via LDS hash,
// then the winning (l, off) candidate writes {1, 1, lx, ly} to its cell.
__global__ __launch_bounds__(256) void scatter_kernel(const float* __restrict__ locs,
                                                      float* __restrict__ out) {
    __shared__ int s_key[TABLE];
    __shared__ int s_val[TABLE];

    const int b = blockIdx.x;
    const float* bl = locs + (size_t)b * NLOCS * 2;
    float* bo = out + (size_t)b * GDIM * GDIM * 4;

    for (int i = threadIdx.x; i < TABLE; i += blockDim.x) {
        s_key[i] = -1;
        s_val[i] = -1;
    }
    __syncthreads();

    // ---- phase 1: insert (cell -> max ordinal) ----
    for (int c = threadIdx.x; c < NLOCS * 4; c += blockDim.x) {
        int l = c >> 2, o = c & 3;
        float lx = bl[l * 2 + 0];
        float ly = bl[l * 2 + 1];
        int px = (int)(lx * 4.0f) + ((o >> 1) - 1);   // offsets (-1,-1),(-1,0),(0,-1),(0,0)
        int py = (int)(ly * 4.0f) + ((o & 1) - 1);
        if (px < 0 || px > GDIM - 1 || py < 0 || py > GDIM - 1) continue;
        int cell = px * GDIM + py;
        unsigned h = ((unsigned)cell * 2654435761u) >> 19;   // top 13 bits -> 8192
        for (;;) {
            int old = atomicCAS(&s_key[h], -1, cell);
            if (old == -1 || old == cell) { atomicMax(&s_val[h], l); break; }
            h = (h + 1) & (TABLE - 1);
        }
    }
    __syncthreads();

    // ---- phase 2: winner writes its cell ----
    for (int c = threadIdx.x; c < NLOCS * 4; c += blockDim.x) {
        int l = c >> 2, o = c & 3;
        float lx = bl[l * 2 + 0];
        float ly = bl[l * 2 + 1];
        int px = (int)(lx * 4.0f) + ((o >> 1) - 1);
        int py = (int)(ly * 4.0f) + ((o & 1) - 1);
        if (px < 0 || px > GDIM - 1 || py < 0 || py > GDIM - 1) continue;
        int cell = px * GDIM + py;
        unsigned h = ((unsigned)cell * 2654435761u) >> 19;
        while (s_key[h] != cell) h = (h + 1) & (TABLE - 1);
        if (s_val[h] == l) {
            float4 v;
            v.x = 1.0f; v.y = 1.0f; v.z = lx; v.w = ly;
            *reinterpret_cast<float4*>(bo + (size_t)cell * 4) = v;
        }
    }
}

extern "C" void kernel_launch(void* const* d_in, const int* in_sizes, int n_in,
                              void* d_out, int out_size, void* d_ws, size_t ws_size,
                              hipStream_t stream) {
    const float* locs = (const float*)d_in[0];
    float* out = (float*)d_out;

    dim3 fill_grid((GDIM + 255) / 256, BATCH * GDIM);
    fill_kernel<<<fill_grid, 256, 0, stream>>>(out);

    scatter_kernel<<<BATCH, 256, 0, stream>>>(locs, out);
}

// Round 3
// 553.923 us; speedup vs baseline: 1.0373x; 1.0373x over previous
//
#include <hip/hip_runtime.h>

#define GDIM   2045
#define BATCH  8
#define NLOCS  1024
#define TABLE  8192   // hash slots; 4096 candidates -> load factor 0.5

typedef float f4 __attribute__((ext_vector_type(4)));   // clang vector: OK for nontemporal builtins

// ---------------- Kernel 1: dense base-map fill ----------------
// out[b][row][col][0..3] = {0.634, 0.634, xs[col], xs[row]}
// One block per (b,row) line: 16360 blocks x 256 threads, 8 float4 stores
// per thread, coalesced along cols, nontemporal (pure 535 MB write stream).
__global__ __launch_bounds__(256) void fill_kernel(float* __restrict__ out) {
    const float DELTA_MAP = (511.0f - 0.5f) / 2045.0f;   // fp32, matches jnp
    const int rowid = blockIdx.x;          // = b*GDIM + row
    const int row   = rowid % GDIM;        // uniform per block -> SALU
    const float gy  = 0.5f + DELTA_MAP * (float)row;
    f4* __restrict__ base = reinterpret_cast<f4*>(out) + (size_t)rowid * GDIM;
    #pragma unroll
    for (int i = 0; i < 8; ++i) {
        const int col = (int)threadIdx.x + i * 256;
        if (col < GDIM) {
            f4 v;
            v.x = 0.634f;
            v.y = 0.634f;
            v.z = 0.5f + DELTA_MAP * (float)col;   // gx: varies along cols (ch 2)
            v.w = gy;                               // gy: varies along rows (ch 3)
            __builtin_nontemporal_store(v, base + col);
        }
    }
}

// ---------------- Kernel 2: sparse hit scatter ----------------
// One block per batch, 1024 threads. Resolve per-cell winner = max ordinal
// via LDS open-addressing hash, then winner writes {1, 1, lx, ly}.
__global__ __launch_bounds__(1024) void scatter_kernel(const float* __restrict__ locs,
                                                       float* __restrict__ out) {
    __shared__ int s_key[TABLE];
    __shared__ int s_val[TABLE];

    const int b = blockIdx.x;
    const float* bl = locs + (size_t)b * NLOCS * 2;
    float* bo = out + (size_t)b * GDIM * GDIM * 4;

    for (int i = threadIdx.x; i < TABLE; i += blockDim.x) {
        s_key[i] = -1;
        s_val[i] = -1;
    }
    __syncthreads();

    // ---- phase 1: insert (cell -> max ordinal) ----
    for (int c = threadIdx.x; c < NLOCS * 4; c += blockDim.x) {
        int l = c >> 2, o = c & 3;
        float lx = bl[l * 2 + 0];
        float ly = bl[l * 2 + 1];
        int px = (int)(lx * 4.0f) + ((o >> 1) - 1);   // offsets (-1,-1),(-1,0),(0,-1),(0,0)
        int py = (int)(ly * 4.0f) + ((o & 1) - 1);
        if (px < 0 || px > GDIM - 1 || py < 0 || py > GDIM - 1) continue;
        int cell = px * GDIM + py;
        unsigned h = ((unsigned)cell * 2654435761u) >> 19;   // top 13 bits -> 8192
        for (;;) {
            int old = atomicCAS(&s_key[h], -1, cell);
            if (old == -1 || old == cell) { atomicMax(&s_val[h], l); break; }
            h = (h + 1) & (TABLE - 1);
        }
    }
    __syncthreads();

    // ---- phase 2: winner writes its cell ----
    for (int c = threadIdx.x; c < NLOCS * 4; c += blockDim.x) {
        int l = c >> 2, o = c & 3;
        float lx = bl[l * 2 + 0];
        float ly = bl[l * 2 + 1];
        int px = (int)(lx * 4.0f) + ((o >> 1) - 1);
        int py = (int)(ly * 4.0f) + ((o & 1) - 1);
        if (px < 0 || px > GDIM - 1 || py < 0 || py > GDIM - 1) continue;
        int cell = px * GDIM + py;
        unsigned h = ((unsigned)cell * 2654435761u) >> 19;
        while (s_key[h] != cell) h = (h + 1) & (TABLE - 1);
        if (s_val[h] == l) {
            float lx2 = lx, ly2 = ly;
            f4 v;
            v.x = 1.0f; v.y = 1.0f; v.z = lx2; v.w = ly2;
            *reinterpret_cast<f4*>(bo + (size_t)cell * 4) = v;
        }
    }
}

extern "C" void kernel_launch(void* const* d_in, const int* in_sizes, int n_in,
                              void* d_out, int out_size, void* d_ws, size_t ws_size,
                              hipStream_t stream) {
    const float* locs = (const float*)d_in[0];
    float* out = (float*)d_out;

    fill_kernel<<<BATCH * GDIM, 256, 0, stream>>>(out);
    scatter_kernel<<<BATCH, 1024, 0, stream>>>(locs, out);
}

// Round 4
// 521.889 us; speedup vs baseline: 1.1009x; 1.0614x over previous
//
#include <hip/hip_runtime.h>

#define GDIM   2045
#define BATCH  8
#define NLOCS  1024
#define TABLE  8192   // hash slots; 4096 candidates -> load factor 0.5
#define TOTAL  33456200u   // 8 * 2045 * 2045 float4 cells

typedef float f4 __attribute__((ext_vector_type(4)));

// ---------------- Kernel 1: dense base-map fill ----------------
// out[b][row][col][0..3] = {0.634, 0.634, xs[col], xs[row]}
// Flat grid-stride over all 33.46M float4 cells, plain cached stores,
// every wave writes a 1024B-aligned contiguous segment (memcpy-like,
// mirrors the rocclr fillBuffer structure that hits 6.2 TB/s here).
__global__ __launch_bounds__(256) void fill_kernel(float* __restrict__ out) {
    const float DELTA_MAP = (511.0f - 0.5f) / 2045.0f;   // fp32, matches jnp
    f4* __restrict__ o = reinterpret_cast<f4*>(out);
    const unsigned stride = gridDim.x * 256u;
    for (unsigned f = blockIdx.x * 256u + threadIdx.x; f < TOTAL; f += stride) {
        unsigned q   = f / 2045u;          // magic-mul div (b*2045 + row)
        unsigned col = f - q * 2045u;
        unsigned row = q % 2045u;          // magic-mul div
        f4 v;
        v.x = 0.634f;
        v.y = 0.634f;
        v.z = 0.5f + DELTA_MAP * (float)col;   // gx: varies along cols (ch 2)
        v.w = 0.5f + DELTA_MAP * (float)row;   // gy: varies along rows (ch 3)
        o[f] = v;
    }
}

// ---------------- Kernel 2: sparse hit scatter ----------------
// One block per batch, 1024 threads. Resolve per-cell winner = max ordinal
// via LDS open-addressing hash, then winner writes {1, 1, lx, ly}.
__global__ __launch_bounds__(1024) void scatter_kernel(const float* __restrict__ locs,
                                                       float* __restrict__ out) {
    __shared__ int s_key[TABLE];
    __shared__ int s_val[TABLE];

    const int b = blockIdx.x;
    const float* bl = locs + (size_t)b * NLOCS * 2;
    float* bo = out + (size_t)b * GDIM * GDIM * 4;

    for (int i = threadIdx.x; i < TABLE; i += blockDim.x) {
        s_key[i] = -1;
        s_val[i] = -1;
    }
    __syncthreads();

    // ---- phase 1: insert (cell -> max ordinal) ----
    for (int c = threadIdx.x; c < NLOCS * 4; c += blockDim.x) {
        int l = c >> 2, o = c & 3;
        float lx = bl[l * 2 + 0];
        float ly = bl[l * 2 + 1];
        int px = (int)(lx * 4.0f) + ((o >> 1) - 1);   // offsets (-1,-1),(-1,0),(0,-1),(0,0)
        int py = (int)(ly * 4.0f) + ((o & 1) - 1);
        if (px < 0 || px > GDIM - 1 || py < 0 || py > GDIM - 1) continue;
        int cell = px * GDIM + py;
        unsigned h = ((unsigned)cell * 2654435761u) >> 19;   // top 13 bits -> 8192
        for (;;) {
            int old = atomicCAS(&s_key[h], -1, cell);
            if (old == -1 || old == cell) { atomicMax(&s_val[h], l); break; }
            h = (h + 1) & (TABLE - 1);
        }
    }
    __syncthreads();

    // ---- phase 2: winner writes its cell ----
    for (int c = threadIdx.x; c < NLOCS * 4; c += blockDim.x) {
        int l = c >> 2, o = c & 3;
        float lx = bl[l * 2 + 0];
        float ly = bl[l * 2 + 1];
        int px = (int)(lx * 4.0f) + ((o >> 1) - 1);
        int py = (int)(ly * 4.0f) + ((o & 1) - 1);
        if (px < 0 || px > GDIM - 1 || py < 0 || py > GDIM - 1) continue;
        int cell = px * GDIM + py;
        unsigned h = ((unsigned)cell * 2654435761u) >> 19;
        while (s_key[h] != cell) h = (h + 1) & (TABLE - 1);
        if (s_val[h] == l) {
            f4 v;
            v.x = 1.0f; v.y = 1.0f; v.z = lx; v.w = ly;
            *reinterpret_cast<f4*>(bo + (size_t)cell * 4) = v;
        }
    }
}

extern "C" void kernel_launch(void* const* d_in, const int* in_sizes, int n_in,
                              void* d_out, int out_size, void* d_ws, size_t ws_size,
                              hipStream_t stream) {
    const float* locs = (const float*)d_in[0];
    float* out = (float*)d_out;

    fill_kernel<<<16384, 256, 0, stream>>>(out);
    scatter_kernel<<<BATCH, 1024, 0, stream>>>(locs, out);
}

// Round 6
// 520.592 us; speedup vs baseline: 1.1037x; 1.0025x over previous
//
#include <hip/hip_runtime.h>

#define GDIM   2045
#define BATCH  8
#define NLOCS  1024
#define TABLE  8192        // hash slots; 4096 candidates -> load factor 0.5
#define NROWS  (BATCH * GDIM)          // 16360 "global rows" (b*2045 + row)
#define FILLB  NROWS                    // 16360 blocks -> stride = 16360*256 = 2048*2045

typedef float f4 __attribute__((ext_vector_type(4)));

// ---------------- Kernel 1: dense base-map fill ----------------
// out[b][row][col][0..3] = {0.634, 0.634, xs[col], xs[row]}
// Grid-stride chosen as an exact multiple of 2045: stride/2045 = 2048.
// => col is loop-invariant (one div at entry); q += 2048; row = q%2045
// advances by +3 with a cheap wrap. Loop body: add, cond-sub, cvt+fma, store.
__global__ __launch_bounds__(256) void fill_kernel(float* __restrict__ out) {
    const float DELTA_MAP = (511.0f - 0.5f) / 2045.0f;   // fp32, matches jnp
    f4* __restrict__ o = reinterpret_cast<f4*>(out);

    unsigned f0  = blockIdx.x * 256u + threadIdx.x;      // < 4,188,160
    unsigned q   = f0 / 2045u;                            // magic-mul, once
    unsigned col = f0 - q * 2045u;                        // loop-invariant
    unsigned row = q % 2045u;                             // magic-mul, once

    const float gx = 0.5f + DELTA_MAP * (float)col;

    while (q < (unsigned)NROWS) {
        f4 v;
        v.x = 0.634f;
        v.y = 0.634f;
        v.z = gx;                                  // varies along cols (ch 2)
        v.w = 0.5f + DELTA_MAP * (float)row;       // varies along rows (ch 3)
        o[(size_t)q * GDIM + col] = v;
        q += 2048u;                                // stride/2045
        row += 3u;                                 // 2048 mod 2045
        if (row >= (unsigned)GDIM) row -= (unsigned)GDIM;
    }
}

// ---------------- Kernel 2: sparse hit scatter ----------------
// One block per batch, 1024 threads. Resolve per-cell winner = max ordinal
// via LDS open-addressing hash, then winner writes {1, 1, lx, ly}.
__global__ __launch_bounds__(1024) void scatter_kernel(const float* __restrict__ locs,
                                                       float* __restrict__ out) {
    __shared__ int s_key[TABLE];
    __shared__ int s_val[TABLE];

    const int b = blockIdx.x;
    const float* bl = locs + (size_t)b * NLOCS * 2;
    float* bo = out + (size_t)b * GDIM * GDIM * 4;

    for (int i = threadIdx.x; i < TABLE; i += blockDim.x) {
        s_key[i] = -1;
        s_val[i] = -1;
    }
    __syncthreads();

    // ---- phase 1: insert (cell -> max ordinal) ----
    for (int c = threadIdx.x; c < NLOCS * 4; c += blockDim.x) {
        int l = c >> 2, o = c & 3;
        float lx = bl[l * 2 + 0];
        float ly = bl[l * 2 + 1];
        int px = (int)(lx * 4.0f) + ((o >> 1) - 1);   // offsets (-1,-1),(-1,0),(0,-1),(0,0)
        int py = (int)(ly * 4.0f) + ((o & 1) - 1);
        if (px < 0 || px > GDIM - 1 || py < 0 || py > GDIM - 1) continue;
        int cell = px * GDIM + py;
        unsigned h = ((unsigned)cell * 2654435761u) >> 19;   // top 13 bits -> 8192
        for (;;) {
            int old = atomicCAS(&s_key[h], -1, cell);
            if (old == -1 || old == cell) { atomicMax(&s_val[h], l); break; }
            h = (h + 1) & (TABLE - 1);
        }
    }
    __syncthreads();

    // ---- phase 2: winner writes its cell ----
    for (int c = threadIdx.x; c < NLOCS * 4; c += blockDim.x) {
        int l = c >> 2, o = c & 3;
        float lx = bl[l * 2 + 0];
        float ly = bl[l * 2 + 1];
        int px = (int)(lx * 4.0f) + ((o >> 1) - 1);
        int py = (int)(ly * 4.0f) + ((o & 1) - 1);
        if (px < 0 || px > GDIM - 1 || py < 0 || py > GDIM - 1) continue;
        int cell = px * GDIM + py;
        unsigned h = ((unsigned)cell * 2654435761u) >> 19;
        while (s_key[h] != cell) h = (h + 1) & (TABLE - 1);
        if (s_val[h] == l) {
            f4 v;
            v.x = 1.0f; v.y = 1.0f; v.z = lx; v.w = ly;
            *reinterpret_cast<f4*>(bo + (size_t)cell * 4) = v;
        }
    }
}

extern "C" void kernel_launch(void* const* d_in, const int* in_sizes, int n_in,
                              void* d_out, int out_size, void* d_ws, size_t ws_size,
                              hipStream_t stream) {
    const float* locs = (const float*)d_in[0];
    float* out = (float*)d_out;

    fill_kernel<<<FILLB, 256, 0, stream>>>(out);
    scatter_kernel<<<BATCH, 1024, 0, stream>>>(locs, out);
}